// Round 1
// baseline (4741.626 us; speedup 1.0000x reference)
//
#include <hip/hip_runtime.h>

// Problem constants (from reference)
#define N0_ 1000000
#define N1_ 200000
#define N2_ 20000
#define N3_ 2048
#define E0_ 2000000
#define E1_ 200000
#define E2_ 20480
#define IN_ 128
#define HID_ 256
#define OUT_ 47

// ---------------- workspace layout (in floats) ----------------
// zeroed region first (one memset), then h1/h2 scratch
static constexpr size_t OFF_AGG0 = 0;                                   // N1*IN
static constexpr size_t OFF_DEG0 = OFF_AGG0 + (size_t)N1_ * IN_;        // N1
static constexpr size_t OFF_AGG1 = OFF_DEG0 + (size_t)N1_;              // N2*HID
static constexpr size_t OFF_DEG1 = OFF_AGG1 + (size_t)N2_ * HID_;       // N2
static constexpr size_t OFF_AGG2 = OFF_DEG1 + (size_t)N2_;              // N3*HID
static constexpr size_t OFF_DEG2 = OFF_AGG2 + (size_t)N3_ * HID_;       // N3
static constexpr size_t ZERO_END = OFF_DEG2 + (size_t)N3_;
static constexpr size_t OFF_H1   = ZERO_END;                            // N1*HID
static constexpr size_t OFF_H2   = OFF_H1 + (size_t)N1_ * HID_;         // N2*HID
static constexpr size_t WS_FLOATS = OFF_H2 + (size_t)N2_ * HID_;        // ~87.8M floats (~351 MB)

// ---------------- scatter + mean accumulate (atomics) ----------------
// F floats per row; F/4 lanes per edge, each lane does a float4 gather and 4 atomicAdds.
template <int F>
__global__ __launch_bounds__(256) void scatter_mean_sum(
    const float* __restrict__ h, const int* __restrict__ src,
    const int* __restrict__ dst, float* __restrict__ agg,
    float* __restrict__ deg, int nE) {
  constexpr int LPE = F / 4;
  int gid = blockIdx.x * 256 + threadIdx.x;
  int e = gid / LPE;
  int c = gid % LPE;
  if (e >= nE) return;
  int s = src[e];
  int d = dst[e];
  float4 v = *reinterpret_cast<const float4*>(h + (size_t)s * F + c * 4);
  float* o = agg + (size_t)d * F + c * 4;
  atomicAdd(o + 0, v.x);
  atomicAdd(o + 1, v.y);
  atomicAdd(o + 2, v.z);
  atomicAdd(o + 3, v.w);
  if (c == 0) atomicAdd(deg + d, 1.0f);
}

// ---------------- fused SAGE GEMM (fp32, vector ALU) ----------------
// out[M x 256] = relu( [Abase | agg/max(deg,1)] @ [Wself; Wneigh] + bias )
// A is M x (2*KHALF) logically; tiles BM=64, BN=64, BK=64; 256 threads, 4x4/thread.
template <int KHALF>
__global__ __launch_bounds__(256) void sage_gemm_relu(
    const float* __restrict__ Abase,   // M x KHALF
    const float* __restrict__ agg,     // M x KHALF
    const float* __restrict__ deg,     // M
    const float* __restrict__ Wself,   // KHALF x 256
    const float* __restrict__ Wneigh,  // KHALF x 256
    const float* __restrict__ bias,    // 256
    float* __restrict__ out,           // M x 256
    int M) {
  constexpr int BK = 64;
  __shared__ float As[64][68];  // [m][k], padded
  __shared__ float Bs[64][64];  // [k][n]

  const int tid = threadIdx.x;
  const int tx = tid & 15;          // n-dim
  const int ty = tid >> 4;          // m-dim
  const int tm = ty * 4;
  const int tn = tx * 4;
  const int m0 = blockIdx.x * 64;
  const int n0 = blockIdx.y * 64;

  float acc[4][4];
#pragma unroll
  for (int r = 0; r < 4; r++)
#pragma unroll
    for (int n = 0; n < 4; n++) acc[r][n] = 0.0f;

  const int colk = (tid & 15) * 4;   // k-offset within tile for A loads
  const int lrow = tid >> 4;         // base row for loads

  for (int kt = 0; kt < 2 * KHALF; kt += BK) {
    const bool selfpart = (kt < KHALF);
    const int kg = (selfpart ? kt : kt - KHALF) + colk;
    // A tile: 64 rows x 64 k
#pragma unroll
    for (int i = 0; i < 4; i++) {
      int row = lrow + i * 16;
      int rowg = m0 + row;
      rowg = rowg < M ? rowg : M - 1;
      float4 v;
      if (selfpart) {
        v = *reinterpret_cast<const float4*>(&Abase[(size_t)rowg * KHALF + kg]);
      } else {
        v = *reinterpret_cast<const float4*>(&agg[(size_t)rowg * KHALF + kg]);
        float inv = 1.0f / fmaxf(deg[rowg], 1.0f);
        v.x *= inv; v.y *= inv; v.z *= inv; v.w *= inv;
      }
      *reinterpret_cast<float4*>(&As[row][colk]) = v;
    }
    // B tile: 64 k x 64 n
#pragma unroll
    for (int i = 0; i < 4; i++) {
      int krow = lrow + i * 16;
      int kgb = kt + krow;
      const float* Wp = selfpart
          ? &Wself[(size_t)kgb * 256 + n0 + tn]
          : &Wneigh[(size_t)(kgb - KHALF) * 256 + n0 + tn];
      *reinterpret_cast<float4*>(&Bs[krow][tn]) = *reinterpret_cast<const float4*>(Wp);
    }
    __syncthreads();

#pragma unroll 4
    for (int k4 = 0; k4 < BK; k4 += 4) {
      float a[4][4], b[4][4];
#pragma unroll
      for (int r = 0; r < 4; r++)
        *reinterpret_cast<float4*>(&a[r][0]) =
            *reinterpret_cast<const float4*>(&As[tm + r][k4]);
#pragma unroll
      for (int j = 0; j < 4; j++)
        *reinterpret_cast<float4*>(&b[j][0]) =
            *reinterpret_cast<const float4*>(&Bs[k4 + j][tn]);
#pragma unroll
      for (int r = 0; r < 4; r++)
#pragma unroll
        for (int j = 0; j < 4; j++)
#pragma unroll
          for (int n = 0; n < 4; n++)
            acc[r][n] = fmaf(a[r][j], b[j][n], acc[r][n]);
    }
    __syncthreads();
  }

  float4 bv = *reinterpret_cast<const float4*>(&bias[n0 + tn]);
#pragma unroll
  for (int r = 0; r < 4; r++) {
    int rowg = m0 + tm + r;
    if (rowg < M) {
      float4 o;
      o.x = fmaxf(acc[r][0] + bv.x, 0.0f);
      o.y = fmaxf(acc[r][1] + bv.y, 0.0f);
      o.z = fmaxf(acc[r][2] + bv.z, 0.0f);
      o.w = fmaxf(acc[r][3] + bv.w, 0.0f);
      *reinterpret_cast<float4*>(&out[(size_t)rowg * 256 + n0 + tn]) = o;
    }
  }
}

// ---------------- final layer: M=2048, K=512, N=47, no relu ----------------
__global__ __launch_bounds__(64) void sage_gemm_out(
    const float* __restrict__ h,    // N2 x 256 (only first N3 rows used)
    const float* __restrict__ agg,  // N3 x 256
    const float* __restrict__ deg,  // N3
    const float* __restrict__ Ws,   // 256 x 47
    const float* __restrict__ Wn,   // 256 x 47
    const float* __restrict__ bias, // 47
    float* __restrict__ out) {      // N3 x 47
  __shared__ float As[512];
  const int row = blockIdx.x;
  const int t = threadIdx.x;
  const float inv = 1.0f / fmaxf(deg[row], 1.0f);
#pragma unroll
  for (int i = 0; i < 2; i++) {
    int idx = t * 8 + i * 4;
    float4 v;
    if (idx < 256) {
      v = *reinterpret_cast<const float4*>(&h[(size_t)row * 256 + idx]);
    } else {
      v = *reinterpret_cast<const float4*>(&agg[(size_t)row * 256 + (idx - 256)]);
      v.x *= inv; v.y *= inv; v.z *= inv; v.w *= inv;
    }
    *reinterpret_cast<float4*>(&As[idx]) = v;
  }
  __syncthreads();
  if (t < OUT_) {
    float s = bias[t];
#pragma unroll 8
    for (int k = 0; k < 256; k++) s = fmaf(As[k], Ws[k * 47 + t], s);
#pragma unroll 8
    for (int k = 0; k < 256; k++) s = fmaf(As[256 + k], Wn[k * 47 + t], s);
    out[(size_t)row * 47 + t] = s;
  }
}

extern "C" void kernel_launch(void* const* d_in, const int* in_sizes, int n_in,
                              void* d_out, int out_size, void* d_ws, size_t ws_size,
                              hipStream_t stream) {
  const float* x      = (const float*)d_in[0];
  const int*   src0   = (const int*)d_in[1];
  const int*   dst0   = (const int*)d_in[2];
  const int*   src1   = (const int*)d_in[3];
  const int*   dst1   = (const int*)d_in[4];
  const int*   src2   = (const int*)d_in[5];
  const int*   dst2   = (const int*)d_in[6];
  const float* Wself0 = (const float*)d_in[7];
  const float* Wneigh0= (const float*)d_in[8];
  const float* b0     = (const float*)d_in[9];
  const float* Wself1 = (const float*)d_in[10];
  const float* Wneigh1= (const float*)d_in[11];
  const float* b1     = (const float*)d_in[12];
  const float* Wself2 = (const float*)d_in[13];
  const float* Wneigh2= (const float*)d_in[14];
  const float* b2     = (const float*)d_in[15];
  float* ws = (float*)d_ws;
  float* out = (float*)d_out;

  // zero all accumulators (agg*/deg*) in one shot
  hipMemsetAsync(d_ws, 0, ZERO_END * sizeof(float), stream);

  // ---- layer 0 ----
  {
    int threads = E0_ * (IN_ / 4);  // 64M
    scatter_mean_sum<IN_><<<(threads + 255) / 256, 256, 0, stream>>>(
        x, src0, dst0, ws + OFF_AGG0, ws + OFF_DEG0, E0_);
    dim3 grid((N1_ + 63) / 64, 4);
    sage_gemm_relu<IN_><<<grid, 256, 0, stream>>>(
        x, ws + OFF_AGG0, ws + OFF_DEG0, Wself0, Wneigh0, b0, ws + OFF_H1, N1_);
  }
  // ---- layer 1 ----
  {
    int threads = E1_ * (HID_ / 4);  // 12.8M
    scatter_mean_sum<HID_><<<(threads + 255) / 256, 256, 0, stream>>>(
        ws + OFF_H1, src1, dst1, ws + OFF_AGG1, ws + OFF_DEG1, E1_);
    dim3 grid((N2_ + 63) / 64, 4);
    sage_gemm_relu<HID_><<<grid, 256, 0, stream>>>(
        ws + OFF_H1, ws + OFF_AGG1, ws + OFF_DEG1, Wself1, Wneigh1, b1, ws + OFF_H2, N2_);
  }
  // ---- layer 2 ----
  {
    int threads = E2_ * (HID_ / 4);
    scatter_mean_sum<HID_><<<(threads + 255) / 256, 256, 0, stream>>>(
        ws + OFF_H2, src2, dst2, ws + OFF_AGG2, ws + OFF_DEG2, E2_);
    sage_gemm_out<<<N3_, 64, 0, stream>>>(
        ws + OFF_H2, ws + OFF_AGG2, ws + OFF_DEG2, Wself2, Wneigh2, b2, out);
  }
}

// Round 2
// 1104.341 us; speedup vs baseline: 4.2936x; 4.2936x over previous
//
#include <hip/hip_runtime.h>

// Problem constants (from reference)
#define N0_ 1000000
#define N1_ 200000
#define N2_ 20000
#define N3_ 2048
#define E0_ 2000000
#define E1_ 200000
#define E2_ 20480
#define IN_ 128
#define HID_ 256
#define OUT_ 47

// ---------------- workspace layout (in 4-byte units) ----------------
static constexpr size_t OFF_CNT  = 0;                 // max(N1) ints, reused as cursor
static constexpr size_t OFF_RPTR = 200000;            // N1+1 ints max
static constexpr size_t OFF_BSUM = 400064;            // 128 ints
static constexpr size_t OFF_EIDS = 400192;            // E0 max ints
static constexpr size_t OFF_A    = 2400192;           // 25.6M floats (HN0; later HN1, HN2)
static constexpr size_t OFF_B    = 28000192;          // 51.2M floats (H1)
static constexpr size_t OFF_C    = 79200192;          // 5.12M floats (H2)
// end: 84,320,192 units = 337 MB

// ---------------- CSR build ----------------
__global__ __launch_bounds__(256) void hist_kernel(const int* __restrict__ dst,
                                                   int* __restrict__ cnt, int nE) {
  int e = blockIdx.x * 256 + threadIdx.x;
  if (e < nE) atomicAdd(&cnt[dst[e]], 1);
}

// per-block exclusive scan over 2048 elements (256 thr x 8)
__global__ __launch_bounds__(256) void scan_local(const int* __restrict__ in,
                                                  int* __restrict__ out,
                                                  int* __restrict__ bsum, int n) {
  __shared__ int s[256];
  const int b = blockIdx.x, t = threadIdx.x;
  const int base = b * 2048 + t * 8;
  int v[8];
  int sum = 0;
#pragma unroll
  for (int i = 0; i < 8; i++) {
    int idx = base + i;
    int x = (idx < n) ? in[idx] : 0;
    v[i] = sum;
    sum += x;
  }
  s[t] = sum;
  __syncthreads();
  for (int off = 1; off < 256; off <<= 1) {
    int x = 0;
    if (t >= off) x = s[t - off];
    __syncthreads();
    if (t >= off) s[t] += x;
    __syncthreads();
  }
  const int texcl = s[t] - sum;  // exclusive prefix of this thread within block
#pragma unroll
  for (int i = 0; i < 8; i++) {
    int idx = base + i;
    if (idx < n) out[idx] = texcl + v[i];
  }
  if (t == 255) bsum[b] = s[255];
}

__global__ void scan_bsum(int* bsum, int nb) {
  if (threadIdx.x == 0 && blockIdx.x == 0) {
    int a = 0;
    for (int i = 0; i < nb; i++) { a += bsum[i]; bsum[i] = a; }
  }
}

__global__ __launch_bounds__(256) void scan_add(int* __restrict__ rptr,
                                                const int* __restrict__ bsum,
                                                int n, int E) {
  const int b = blockIdx.x, t = threadIdx.x;
  const int add = (b == 0) ? 0 : bsum[b - 1];
  const int base = b * 2048 + t * 8;
#pragma unroll
  for (int i = 0; i < 8; i++) {
    int idx = base + i;
    if (idx < n) rptr[idx] += add;
  }
  if (b == 0 && t == 0) rptr[n] = E;
}

__global__ __launch_bounds__(256) void csr_fill(const int* __restrict__ src,
                                                const int* __restrict__ dst,
                                                const int* __restrict__ rptr,
                                                int* __restrict__ cursor,
                                                int* __restrict__ eids, int nE) {
  int e = blockIdx.x * 256 + threadIdx.x;
  if (e >= nE) return;
  int d = dst[e];
  int pos = rptr[d] + atomicAdd(&cursor[d], 1);
  eids[pos] = src[e];
}

// ---------------- CSR gather-aggregate + mean (no atomics) ----------------
// one wave per dst row; lane owns F/64 columns
template <int F>
__global__ __launch_bounds__(256) void csr_agg_mean(
    const float* __restrict__ h, const int* __restrict__ eids,
    const int* __restrict__ rptr, float* __restrict__ out, int M) {
  constexpr int C = F / 64;  // 2 or 4 floats per lane
  const int wid = (blockIdx.x * 256 + threadIdx.x) >> 6;
  const int lane = threadIdx.x & 63;
  if (wid >= M) return;
  const int beg = rptr[wid], end = rptr[wid + 1];
  float acc[C];
#pragma unroll
  for (int i = 0; i < C; i++) acc[i] = 0.0f;
  for (int i = beg; i < end; i++) {
    const int s = eids[i];
    const float* p = h + (size_t)s * F + lane * C;
    if (C == 2) {
      float2 v = *reinterpret_cast<const float2*>(p);
      acc[0] += v.x; acc[1] += v.y;
    } else {
      float4 v = *reinterpret_cast<const float4*>(p);
      acc[0] += v.x; acc[1] += v.y; acc[2] += v.z; acc[3] += v.w;
    }
  }
  const float inv = 1.0f / fmaxf((float)(end - beg), 1.0f);
  float* o = out + (size_t)wid * F + lane * C;
  if (C == 2) {
    float2 v; v.x = acc[0] * inv; v.y = acc[1] * inv;
    *reinterpret_cast<float2*>(o) = v;
  } else {
    float4 v; v.x = acc[0] * inv; v.y = acc[1] * inv; v.z = acc[2] * inv; v.w = acc[3] * inv;
    *reinterpret_cast<float4*>(o) = v;
  }
}

// ---------------- fused SAGE GEMM (fp32, vector ALU) ----------------
// out[M x 256] = relu( [A0 | A1] @ [Wself; Wneigh] + bias ); A1 already meaned
template <int KHALF>
__global__ __launch_bounds__(256) void sage_gemm_relu(
    const float* __restrict__ A0,      // M x KHALF
    const float* __restrict__ A1,      // M x KHALF (h_neigh, already divided)
    const float* __restrict__ Wself,   // KHALF x 256
    const float* __restrict__ Wneigh,  // KHALF x 256
    const float* __restrict__ bias,    // 256
    float* __restrict__ out,           // M x 256
    int M) {
  constexpr int BK = 64;
  __shared__ float As[64][68];
  __shared__ float Bs[64][64];

  const int tid = threadIdx.x;
  const int tx = tid & 15;
  const int ty = tid >> 4;
  const int tm = ty * 4;
  const int tn = tx * 4;
  const int m0 = blockIdx.x * 64;
  const int n0 = blockIdx.y * 64;

  float acc[4][4];
#pragma unroll
  for (int r = 0; r < 4; r++)
#pragma unroll
    for (int n = 0; n < 4; n++) acc[r][n] = 0.0f;

  const int colk = (tid & 15) * 4;
  const int lrow = tid >> 4;

  for (int kt = 0; kt < 2 * KHALF; kt += BK) {
    const bool selfpart = (kt < KHALF);
    const int kg = (selfpart ? kt : kt - KHALF) + colk;
#pragma unroll
    for (int i = 0; i < 4; i++) {
      int row = lrow + i * 16;
      int rowg = m0 + row;
      rowg = rowg < M ? rowg : M - 1;
      const float* Ap = selfpart ? &A0[(size_t)rowg * KHALF + kg]
                                 : &A1[(size_t)rowg * KHALF + kg];
      *reinterpret_cast<float4*>(&As[row][colk]) =
          *reinterpret_cast<const float4*>(Ap);
    }
#pragma unroll
    for (int i = 0; i < 4; i++) {
      int krow = lrow + i * 16;
      int kgb = kt + krow;
      const float* Wp = selfpart
          ? &Wself[(size_t)kgb * 256 + n0 + tn]
          : &Wneigh[(size_t)(kgb - KHALF) * 256 + n0 + tn];
      *reinterpret_cast<float4*>(&Bs[krow][tn]) = *reinterpret_cast<const float4*>(Wp);
    }
    __syncthreads();

#pragma unroll 4
    for (int k4 = 0; k4 < BK; k4 += 4) {
      float a[4][4], b[4][4];
#pragma unroll
      for (int r = 0; r < 4; r++)
        *reinterpret_cast<float4*>(&a[r][0]) =
            *reinterpret_cast<const float4*>(&As[tm + r][k4]);
#pragma unroll
      for (int j = 0; j < 4; j++)
        *reinterpret_cast<float4*>(&b[j][0]) =
            *reinterpret_cast<const float4*>(&Bs[k4 + j][tn]);
#pragma unroll
      for (int r = 0; r < 4; r++)
#pragma unroll
        for (int j = 0; j < 4; j++)
#pragma unroll
          for (int n = 0; n < 4; n++)
            acc[r][n] = fmaf(a[r][j], b[j][n], acc[r][n]);
    }
    __syncthreads();
  }

  float4 bv = *reinterpret_cast<const float4*>(&bias[n0 + tn]);
#pragma unroll
  for (int r = 0; r < 4; r++) {
    int rowg = m0 + tm + r;
    if (rowg < M) {
      float4 o;
      o.x = fmaxf(acc[r][0] + bv.x, 0.0f);
      o.y = fmaxf(acc[r][1] + bv.y, 0.0f);
      o.z = fmaxf(acc[r][2] + bv.z, 0.0f);
      o.w = fmaxf(acc[r][3] + bv.w, 0.0f);
      *reinterpret_cast<float4*>(&out[(size_t)rowg * 256 + n0 + tn]) = o;
    }
  }
}

// ---------------- final layer: M=2048, K=512, N=47, no relu ----------------
__global__ __launch_bounds__(64) void sage_gemm_out(
    const float* __restrict__ h,    // N2 x 256 (first N3 rows used)
    const float* __restrict__ hn,   // N3 x 256 (already meaned)
    const float* __restrict__ Ws,   // 256 x 47
    const float* __restrict__ Wn,   // 256 x 47
    const float* __restrict__ bias, // 47
    float* __restrict__ out) {      // N3 x 47
  __shared__ float As[512];
  const int row = blockIdx.x;
  const int t = threadIdx.x;
#pragma unroll
  for (int i = 0; i < 2; i++) {
    int idx = t * 8 + i * 4;
    float4 v;
    if (idx < 256) {
      v = *reinterpret_cast<const float4*>(&h[(size_t)row * 256 + idx]);
    } else {
      v = *reinterpret_cast<const float4*>(&hn[(size_t)row * 256 + (idx - 256)]);
    }
    *reinterpret_cast<float4*>(&As[idx]) = v;
  }
  __syncthreads();
  if (t < OUT_) {
    float s = bias[t];
#pragma unroll 8
    for (int k = 0; k < 256; k++) s = fmaf(As[k], Ws[k * 47 + t], s);
#pragma unroll 8
    for (int k = 0; k < 256; k++) s = fmaf(As[256 + k], Wn[k * 47 + t], s);
    out[(size_t)row * 47 + t] = s;
  }
}

// ---------------- host-side: CSR build + layer driver ----------------
static void build_csr(const int* src, const int* dst, int E, int M,
                      int* cnt, int* rptr, int* bsum, int* eids,
                      hipStream_t stream) {
  const int nb = (M + 2047) / 2048;
  hipMemsetAsync(cnt, 0, (size_t)M * 4, stream);
  hist_kernel<<<(E + 255) / 256, 256, 0, stream>>>(dst, cnt, E);
  scan_local<<<nb, 256, 0, stream>>>(cnt, rptr, bsum, M);
  scan_bsum<<<1, 64, 0, stream>>>(bsum, nb);
  scan_add<<<nb, 256, 0, stream>>>(rptr, bsum, M, E);
  hipMemsetAsync(cnt, 0, (size_t)M * 4, stream);
  csr_fill<<<(E + 255) / 256, 256, 0, stream>>>(src, dst, rptr, cnt, eids, E);
}

extern "C" void kernel_launch(void* const* d_in, const int* in_sizes, int n_in,
                              void* d_out, int out_size, void* d_ws, size_t ws_size,
                              hipStream_t stream) {
  const float* x      = (const float*)d_in[0];
  const int*   src0   = (const int*)d_in[1];
  const int*   dst0   = (const int*)d_in[2];
  const int*   src1   = (const int*)d_in[3];
  const int*   dst1   = (const int*)d_in[4];
  const int*   src2   = (const int*)d_in[5];
  const int*   dst2   = (const int*)d_in[6];
  const float* Wself0 = (const float*)d_in[7];
  const float* Wneigh0= (const float*)d_in[8];
  const float* b0     = (const float*)d_in[9];
  const float* Wself1 = (const float*)d_in[10];
  const float* Wneigh1= (const float*)d_in[11];
  const float* b1     = (const float*)d_in[12];
  const float* Wself2 = (const float*)d_in[13];
  const float* Wneigh2= (const float*)d_in[14];
  const float* b2     = (const float*)d_in[15];

  int*   wsi = (int*)d_ws;
  float* wsf = (float*)d_ws;
  int*   cnt  = wsi + OFF_CNT;
  int*   rptr = wsi + OFF_RPTR;
  int*   bsum = wsi + OFF_BSUM;
  int*   eids = wsi + OFF_EIDS;
  float* HN0  = wsf + OFF_A;   // N1 x IN
  float* H1   = wsf + OFF_B;   // N1 x HID
  float* HN1  = wsf + OFF_A;   // N2 x HID (reuse A)
  float* H2   = wsf + OFF_C;   // N2 x HID
  float* HN2  = wsf + OFF_A;   // N3 x HID (reuse A)
  float* out  = (float*)d_out;

  // ---- layer 0 ----
  build_csr(src0, dst0, E0_, N1_, cnt, rptr, bsum, eids, stream);
  csr_agg_mean<IN_><<<(N1_ + 3) / 4, 256, 0, stream>>>(x, eids, rptr, HN0, N1_);
  {
    dim3 grid((N1_ + 63) / 64, 4);
    sage_gemm_relu<IN_><<<grid, 256, 0, stream>>>(x, HN0, Wself0, Wneigh0, b0, H1, N1_);
  }
  // ---- layer 1 ----
  build_csr(src1, dst1, E1_, N2_, cnt, rptr, bsum, eids, stream);
  csr_agg_mean<HID_><<<(N2_ + 3) / 4, 256, 0, stream>>>(H1, eids, rptr, HN1, N2_);
  {
    dim3 grid((N2_ + 63) / 64, 4);
    sage_gemm_relu<HID_><<<grid, 256, 0, stream>>>(H1, HN1, Wself1, Wneigh1, b1, H2, N2_);
  }
  // ---- layer 2 ----
  build_csr(src2, dst2, E2_, N3_, cnt, rptr, bsum, eids, stream);
  csr_agg_mean<HID_><<<(N3_ + 3) / 4, 256, 0, stream>>>(H2, eids, rptr, HN2, N3_);
  sage_gemm_out<<<N3_, 64, 0, stream>>>(H2, HN2, Wself2, Wneigh2, b2, out);
}

// Round 3
// 772.170 us; speedup vs baseline: 6.1406x; 1.4302x over previous
//
#include <hip/hip_runtime.h>

#define N0_ 1000000
#define N1_ 200000
#define N2_ 20000
#define N3_ 2048
#define E0_ 2000000
#define E1_ 200000
#define E2_ 20480
#define IN_ 128
#define HID_ 256
#define OUT_ 47

typedef unsigned short u16;
typedef unsigned int u32;
typedef __attribute__((ext_vector_type(8))) short b16x8;
typedef __attribute__((ext_vector_type(4))) float f32x4;
typedef __attribute__((ext_vector_type(4))) u16 u16x4;
typedef __attribute__((ext_vector_type(8))) u16 u16x8;

__device__ __forceinline__ u16 f2b(float f) {  // RNE fp32->bf16
  u32 u = __builtin_bit_cast(u32, f);
  return (u16)((u + 0x7FFFu + ((u >> 16) & 1u)) >> 16);
}
__device__ __forceinline__ float b2f(u16 b) {
  return __builtin_bit_cast(float, (u32)b << 16);
}

// ---------------- workspace layout (4-byte words) ----------------
static constexpr size_t OFF_CNT  = 0;          // 200064
static constexpr size_t OFF_RPTR = 200064;     // 200064
static constexpr size_t OFF_BSUM = 400128;     // 128
static constexpr size_t OFF_EIDS = 400256;     // 2000000
static constexpr size_t OFF_BT0  = 2400256;    // 32768  (256x256 bf16)
static constexpr size_t OFF_BT1  = 2433024;    // 65536  (256x512 bf16)
static constexpr size_t OFF_HN0  = 2498560;    // 12800000 (200000x128 bf16)
static constexpr size_t OFF_H1   = 15298560;   // 25600000 (200000x256 bf16)
static constexpr size_t OFF_HN1  = 40898560;   // 2560000  (20000x256 bf16)
static constexpr size_t OFF_H2   = 43458560;   // 2560000
static constexpr size_t OFF_HN2  = 46018560;   // 262144   (2048x256 bf16)

// ---------------- CSR build ----------------
__global__ __launch_bounds__(256) void hist_kernel(const int* __restrict__ dst,
                                                   int* __restrict__ cnt, int nE) {
  int e = blockIdx.x * 256 + threadIdx.x;
  if (e < nE) atomicAdd(&cnt[dst[e]], 1);
}

__global__ __launch_bounds__(256) void scan_local(const int* __restrict__ in,
                                                  int* __restrict__ out,
                                                  int* __restrict__ bsum, int n) {
  __shared__ int s[256];
  const int b = blockIdx.x, t = threadIdx.x;
  const int base = b * 2048 + t * 8;
  int v[8];
  int sum = 0;
#pragma unroll
  for (int i = 0; i < 8; i++) {
    int idx = base + i;
    int x = (idx < n) ? in[idx] : 0;
    v[i] = sum;
    sum += x;
  }
  s[t] = sum;
  __syncthreads();
  for (int off = 1; off < 256; off <<= 1) {
    int x = 0;
    if (t >= off) x = s[t - off];
    __syncthreads();
    if (t >= off) s[t] += x;
    __syncthreads();
  }
  const int texcl = s[t] - sum;
#pragma unroll
  for (int i = 0; i < 8; i++) {
    int idx = base + i;
    if (idx < n) out[idx] = texcl + v[i];
  }
  if (t == 255) bsum[b] = s[255];
}

__global__ void scan_bsum(int* bsum, int nb) {
  if (threadIdx.x == 0 && blockIdx.x == 0) {
    int a = 0;
    for (int i = 0; i < nb; i++) { a += bsum[i]; bsum[i] = a; }
  }
}

__global__ __launch_bounds__(256) void scan_add(int* __restrict__ rptr,
                                                const int* __restrict__ bsum,
                                                int n, int E) {
  const int b = blockIdx.x, t = threadIdx.x;
  const int add = (b == 0) ? 0 : bsum[b - 1];
  const int base = b * 2048 + t * 8;
#pragma unroll
  for (int i = 0; i < 8; i++) {
    int idx = base + i;
    if (idx < n) rptr[idx] += add;
  }
  if (b == 0 && t == 0) rptr[n] = E;
}

__global__ __launch_bounds__(256) void csr_fill(const int* __restrict__ src,
                                                const int* __restrict__ dst,
                                                const int* __restrict__ rptr,
                                                int* __restrict__ cursor,
                                                int* __restrict__ eids, int nE) {
  int e = blockIdx.x * 256 + threadIdx.x;
  if (e >= nE) return;
  int d = dst[e];
  int pos = rptr[d] + atomicAdd(&cursor[d], 1);
  eids[pos] = src[e];
}

// ---------------- weight pack: Bt[n][k] bf16, k = [Wself; Wneigh] ----------------
__global__ __launch_bounds__(256) void pack_w(const float* __restrict__ Ws,
                                              const float* __restrict__ Wn,
                                              u16* __restrict__ Bt, int KS, int KT) {
  int t = blockIdx.x * 256 + threadIdx.x;  // over 256*KT, n fast for coalesced reads
  if (t >= 256 * KT) return;
  int n = t & 255, k = t >> 8;
  float v = (k < KS) ? Ws[(size_t)k * 256 + n] : Wn[(size_t)(k - KS) * 256 + n];
  Bt[(size_t)n * KT + k] = f2b(v);
}

// ---------------- CSR gather-aggregate + mean ----------------
// layer 0: fp32 source (x), F=128, bf16 out; one wave per row
__global__ __launch_bounds__(256) void agg0(const float* __restrict__ h,
                                            const int* __restrict__ eids,
                                            const int* __restrict__ rptr,
                                            u16* __restrict__ out, int M) {
  int wid = (blockIdx.x * 256 + threadIdx.x) >> 6;
  int lane = threadIdx.x & 63;
  if (wid >= M) return;
  int beg = rptr[wid], end = rptr[wid + 1];
  float a0 = 0.f, a1 = 0.f;
  for (int i = beg; i < end; i++) {
    int s = eids[i];
    float2 v = *reinterpret_cast<const float2*>(&h[(size_t)s * IN_ + lane * 2]);
    a0 += v.x; a1 += v.y;
  }
  float inv = 1.0f / fmaxf((float)(end - beg), 1.0f);
  u32 p = (u32)f2b(a0 * inv) | ((u32)f2b(a1 * inv) << 16);
  *reinterpret_cast<u32*>(&out[(size_t)wid * IN_ + lane * 2]) = p;
}

// layers 1,2: bf16 source, F=256, bf16 out
__global__ __launch_bounds__(256) void agg1(const u16* __restrict__ h,
                                            const int* __restrict__ eids,
                                            const int* __restrict__ rptr,
                                            u16* __restrict__ out, int M) {
  int wid = (blockIdx.x * 256 + threadIdx.x) >> 6;
  int lane = threadIdx.x & 63;
  if (wid >= M) return;
  int beg = rptr[wid], end = rptr[wid + 1];
  float a0 = 0.f, a1 = 0.f, a2 = 0.f, a3 = 0.f;
  for (int i = beg; i < end; i++) {
    int s = eids[i];
    u16x4 v = *reinterpret_cast<const u16x4*>(&h[(size_t)s * HID_ + lane * 4]);
    a0 += b2f(v[0]); a1 += b2f(v[1]); a2 += b2f(v[2]); a3 += b2f(v[3]);
  }
  float inv = 1.0f / fmaxf((float)(end - beg), 1.0f);
  u16x4 o;
  o[0] = f2b(a0 * inv); o[1] = f2b(a1 * inv); o[2] = f2b(a2 * inv); o[3] = f2b(a3 * inv);
  *reinterpret_cast<u16x4*>(&out[(size_t)wid * HID_ + lane * 4]) = o;
}

// ---------------- MFMA GEMM: out[Mx256] = relu([A0|A1] @ Bt^T + bias) ----------------
// BM=64, BN=256, BK=64; 4 waves, wave w owns n-strip w*64; 4x4 16x16x32 frags.
template <int KSELF, bool A0F32>
__global__ __launch_bounds__(256) void sage_gemm_mfma(
    const void* __restrict__ A0v, const u16* __restrict__ A1,
    const u16* __restrict__ Bt, const float* __restrict__ bias,
    u16* __restrict__ outp, int M) {
  constexpr int KTOT = 2 * KSELF;
  __shared__ u16 As[64 * 64];    // [m][k], XOR-swizzled
  __shared__ u16 Bs[256 * 64];   // [n][k], XOR-swizzled
  const int tid = threadIdx.x;
  const int lane = tid & 63;
  const int w = tid >> 6;
  const int m0 = blockIdx.x * 64;

  f32x4 acc[4][4];
#pragma unroll
  for (int m = 0; m < 4; m++)
#pragma unroll
    for (int n = 0; n < 4; n++) acc[m][n] = f32x4{0.f, 0.f, 0.f, 0.f};

  for (int kt = 0; kt < KTOT; kt += 64) {
    // ---- stage A tile (64 rows x 64 k) ----
    if (A0F32 && kt < KSELF) {
      const float* A0 = (const float*)A0v;
#pragma unroll
      for (int i = 0; i < 4; i++) {
        int e = tid + i * 256;           // 0..1023
        int row = e >> 4;
        int c = (e & 15) * 4;
        int rowg = m0 + row; if (rowg >= M) rowg = M - 1;
        float4 v = *reinterpret_cast<const float4*>(&A0[(size_t)rowg * KSELF + kt + c]);
        u32 p0 = (u32)f2b(v.x) | ((u32)f2b(v.y) << 16);
        u32 p1 = (u32)f2b(v.z) | ((u32)f2b(v.w) << 16);
        int byt = ((row * 64 + c) * 2) ^ ((row & 7) << 4);
        u32* dp = reinterpret_cast<u32*>(reinterpret_cast<char*>(As) + byt);
        dp[0] = p0; dp[1] = p1;
      }
    } else {
      const u16* src; int ksrc;
      if (!A0F32 && kt < KSELF) { src = (const u16*)A0v; ksrc = kt; }
      else                      { src = A1;              ksrc = kt - KSELF; }
#pragma unroll
      for (int i = 0; i < 2; i++) {
        int e = tid + i * 256;           // 0..511
        int row = e >> 3;
        int ch = e & 7;
        int rowg = m0 + row; if (rowg >= M) rowg = M - 1;
        u16x8 v = *reinterpret_cast<const u16x8*>(&src[(size_t)rowg * KSELF + ksrc + ch * 8]);
        int byt = ((row * 64 + ch * 8) * 2) ^ ((row & 7) << 4);
        *reinterpret_cast<u16x8*>(reinterpret_cast<char*>(As) + byt) = v;
      }
    }
    // ---- stage B tile (256 n x 64 k) ----
#pragma unroll
    for (int i = 0; i < 8; i++) {
      int e = tid + i * 256;             // 0..2047
      int n = e >> 3;
      int ch = e & 7;
      u16x8 v = *reinterpret_cast<const u16x8*>(&Bt[(size_t)n * KTOT + kt + ch * 8]);
      int byt = ((n * 64 + ch * 8) * 2) ^ ((n & 7) << 4);
      *reinterpret_cast<u16x8*>(reinterpret_cast<char*>(Bs) + byt) = v;
    }
    __syncthreads();
    // ---- compute: 2 k-slices x 16 MFMA ----
#pragma unroll
    for (int kk = 0; kk < 64; kk += 32) {
      const int kb = (kk + (lane >> 4) * 8) * 2;
      b16x8 a[4], b[4];
#pragma unroll
      for (int m = 0; m < 4; m++) {
        int row = m * 16 + (lane & 15);
        int byt = (row * 128 + kb) ^ ((row & 7) << 4);
        a[m] = *reinterpret_cast<const b16x8*>(reinterpret_cast<const char*>(As) + byt);
      }
#pragma unroll
      for (int n = 0; n < 4; n++) {
        int row = w * 64 + n * 16 + (lane & 15);
        int byt = (row * 128 + kb) ^ ((row & 7) << 4);
        b[n] = *reinterpret_cast<const b16x8*>(reinterpret_cast<const char*>(Bs) + byt);
      }
#pragma unroll
      for (int m = 0; m < 4; m++)
#pragma unroll
        for (int n = 0; n < 4; n++)
          acc[m][n] = __builtin_amdgcn_mfma_f32_16x16x32_bf16(a[m], b[n], acc[m][n], 0, 0, 0);
    }
    __syncthreads();
  }
  // ---- epilogue: bias + relu + bf16 store ----
  float bv[4];
#pragma unroll
  for (int n = 0; n < 4; n++) bv[n] = bias[w * 64 + n * 16 + (lane & 15)];
#pragma unroll
  for (int m = 0; m < 4; m++) {
    int rowb = m0 + m * 16 + ((lane >> 4) << 2);
#pragma unroll
    for (int r = 0; r < 4; r++) {
      int row = rowb + r;
      if (row < M) {
#pragma unroll
        for (int n = 0; n < 4; n++) {
          float v = acc[m][n][r] + bv[n];
          v = fmaxf(v, 0.0f);
          outp[(size_t)row * 256 + w * 64 + n * 16 + (lane & 15)] = f2b(v);
        }
      }
    }
  }
}

// ---------------- final layer: M=2048, K=512, N=47, fp32 math, no relu ----------------
__global__ __launch_bounds__(64) void sage_gemm_out(
    const u16* __restrict__ h, const u16* __restrict__ hn,
    const float* __restrict__ Ws, const float* __restrict__ Wn,
    const float* __restrict__ bias, float* __restrict__ out) {
  __shared__ float As[512];
  const int row = blockIdx.x;
  const int t = threadIdx.x;
  u16x4 a = *reinterpret_cast<const u16x4*>(&h[(size_t)row * 256 + t * 4]);
  u16x4 b = *reinterpret_cast<const u16x4*>(&hn[(size_t)row * 256 + t * 4]);
#pragma unroll
  for (int j = 0; j < 4; j++) {
    As[t * 4 + j] = b2f(a[j]);
    As[256 + t * 4 + j] = b2f(b[j]);
  }
  __syncthreads();
  if (t < OUT_) {
    float s = bias[t];
#pragma unroll 8
    for (int k = 0; k < 256; k++) s = fmaf(As[k], Ws[k * 47 + t], s);
#pragma unroll 8
    for (int k = 0; k < 256; k++) s = fmaf(As[256 + k], Wn[k * 47 + t], s);
    out[(size_t)row * 47 + t] = s;
  }
}

// ---------------- host driver ----------------
static void build_csr(const int* src, const int* dst, int E, int M,
                      int* cnt, int* rptr, int* bsum, int* eids,
                      hipStream_t stream) {
  const int nb = (M + 2047) / 2048;
  hipMemsetAsync(cnt, 0, (size_t)M * 4, stream);
  hist_kernel<<<(E + 255) / 256, 256, 0, stream>>>(dst, cnt, E);
  scan_local<<<nb, 256, 0, stream>>>(cnt, rptr, bsum, M);
  scan_bsum<<<1, 64, 0, stream>>>(bsum, nb);
  scan_add<<<nb, 256, 0, stream>>>(rptr, bsum, M, E);
  hipMemsetAsync(cnt, 0, (size_t)M * 4, stream);
  csr_fill<<<(E + 255) / 256, 256, 0, stream>>>(src, dst, rptr, cnt, eids, E);
}

extern "C" void kernel_launch(void* const* d_in, const int* in_sizes, int n_in,
                              void* d_out, int out_size, void* d_ws, size_t ws_size,
                              hipStream_t stream) {
  const float* x      = (const float*)d_in[0];
  const int*   src0   = (const int*)d_in[1];
  const int*   dst0   = (const int*)d_in[2];
  const int*   src1   = (const int*)d_in[3];
  const int*   dst1   = (const int*)d_in[4];
  const int*   src2   = (const int*)d_in[5];
  const int*   dst2   = (const int*)d_in[6];
  const float* Wself0 = (const float*)d_in[7];
  const float* Wneigh0= (const float*)d_in[8];
  const float* b0     = (const float*)d_in[9];
  const float* Wself1 = (const float*)d_in[10];
  const float* Wneigh1= (const float*)d_in[11];
  const float* b1     = (const float*)d_in[12];
  const float* Wself2 = (const float*)d_in[13];
  const float* Wneigh2= (const float*)d_in[14];
  const float* b2     = (const float*)d_in[15];

  int* wsi  = (int*)d_ws;
  int* cnt  = wsi + OFF_CNT;
  int* rptr = wsi + OFF_RPTR;
  int* bsum = wsi + OFF_BSUM;
  int* eids = wsi + OFF_EIDS;
  u16* Bt0  = (u16*)(wsi + OFF_BT0);
  u16* Bt1  = (u16*)(wsi + OFF_BT1);
  u16* HN0  = (u16*)(wsi + OFF_HN0);
  u16* H1   = (u16*)(wsi + OFF_H1);
  u16* HN1  = (u16*)(wsi + OFF_HN1);
  u16* H2   = (u16*)(wsi + OFF_H2);
  u16* HN2  = (u16*)(wsi + OFF_HN2);
  float* out = (float*)d_out;

  // weight packs (tiny)
  pack_w<<<(256 * 256 + 255) / 256, 256, 0, stream>>>(Wself0, Wneigh0, Bt0, IN_, 2 * IN_);
  pack_w<<<(256 * 512 + 255) / 256, 256, 0, stream>>>(Wself1, Wneigh1, Bt1, HID_, 2 * HID_);

  // ---- layer 0 ----
  build_csr(src0, dst0, E0_, N1_, cnt, rptr, bsum, eids, stream);
  agg0<<<(N1_ + 3) / 4, 256, 0, stream>>>(x, eids, rptr, HN0, N1_);
  sage_gemm_mfma<IN_, true><<<N1_ / 64, 256, 0, stream>>>(x, HN0, Bt0, b0, H1, N1_);

  // ---- layer 1 ----
  build_csr(src1, dst1, E1_, N2_, cnt, rptr, bsum, eids, stream);
  agg1<<<(N2_ + 3) / 4, 256, 0, stream>>>(H1, eids, rptr, HN1, N2_);
  sage_gemm_mfma<HID_, false><<<(N2_ + 63) / 64, 256, 0, stream>>>(H1, HN1, Bt1, b1, H2, N2_);

  // ---- layer 2 ----
  build_csr(src2, dst2, E2_, N3_, cnt, rptr, bsum, eids, stream);
  agg1<<<(N3_ + 3) / 4, 256, 0, stream>>>(H2, eids, rptr, HN2, N3_);
  sage_gemm_out<<<N3_, 64, 0, stream>>>(H2, HN2, Wself2, Wneigh2, b2, out);
}

// Round 4
// 659.199 us; speedup vs baseline: 7.1930x; 1.1714x over previous
//
#include <hip/hip_runtime.h>

#define N0_ 1000000
#define N1_ 200000
#define N2_ 20000
#define N3_ 2048
#define E0_ 2000000
#define E1_ 200000
#define E2_ 20480
#define IN_ 128
#define HID_ 256
#define OUT_ 47

typedef unsigned short u16;
typedef unsigned int u32;
typedef __attribute__((ext_vector_type(8))) short b16x8;
typedef __attribute__((ext_vector_type(4))) float f32x4;
typedef __attribute__((ext_vector_type(4))) u16 u16x4;
typedef __attribute__((ext_vector_type(8))) u16 u16x8;

__device__ __forceinline__ u16 f2b(float f) {  // RNE fp32->bf16
  u32 u = __builtin_bit_cast(u32, f);
  return (u16)((u + 0x7FFFu + ((u >> 16) & 1u)) >> 16);
}
__device__ __forceinline__ float b2f(u16 b) {
  return __builtin_bit_cast(float, (u32)b << 16);
}

// ---------------- workspace layout (4-byte words) ----------------
static constexpr size_t OFF_CNT  = 0;          // 200064 (hist counts)
static constexpr size_t OFF_CUR  = 200064;     // 200064 (fill cursors) - adjacent: one memset
static constexpr size_t OFF_RPTR = 400128;     // 200064
static constexpr size_t OFF_BSUM = 600192;     // 128
static constexpr size_t OFF_EIDS = 600320;     // 2000000
static constexpr size_t OFF_BT0  = 2600320;    // 32768  (256x256 bf16)
static constexpr size_t OFF_BT1  = 2633088;    // 65536  (256x512 bf16)
static constexpr size_t OFF_HN0  = 2698624;    // 12800000 (200000x128 bf16)
static constexpr size_t OFF_H1   = 15498624;   // 25600000 (200000x256 bf16)
static constexpr size_t OFF_HN1  = 41098624;   // 2560000  (20000x256 bf16)
static constexpr size_t OFF_H2   = 43658624;   // 2560000
static constexpr size_t OFF_HN2  = 46218624;   // 262144   (2048x256 bf16)

// ---------------- CSR build ----------------
__global__ __launch_bounds__(256) void hist_kernel(const int* __restrict__ dst,
                                                   int* __restrict__ cnt, int nE) {
  int e = blockIdx.x * 256 + threadIdx.x;
  if (e < nE) atomicAdd(&cnt[dst[e]], 1);
}

__global__ __launch_bounds__(256) void scan_local(const int* __restrict__ in,
                                                  int* __restrict__ out,
                                                  int* __restrict__ bsum, int n) {
  __shared__ int s[256];
  const int b = blockIdx.x, t = threadIdx.x;
  const int base = b * 2048 + t * 8;
  int v[8];
  int sum = 0;
#pragma unroll
  for (int i = 0; i < 8; i++) {
    int idx = base + i;
    int x = (idx < n) ? in[idx] : 0;
    v[i] = sum;
    sum += x;
  }
  s[t] = sum;
  __syncthreads();
  for (int off = 1; off < 256; off <<= 1) {
    int x = 0;
    if (t >= off) x = s[t - off];
    __syncthreads();
    if (t >= off) s[t] += x;
    __syncthreads();
  }
  const int texcl = s[t] - sum;
#pragma unroll
  for (int i = 0; i < 8; i++) {
    int idx = base + i;
    if (idx < n) out[idx] = texcl + v[i];
  }
  if (t == 255) bsum[b] = s[255];
}

// adds prefix of bsum (computed redundantly per block, nb<=98) and writes rptr[n]=E
__global__ __launch_bounds__(256) void scan_add(int* __restrict__ rptr,
                                                const int* __restrict__ bsum,
                                                int n, int E) {
  const int b = blockIdx.x, t = threadIdx.x;
  int add = 0;
  for (int i = 0; i < b; i++) add += bsum[i];
  const int base = b * 2048 + t * 8;
#pragma unroll
  for (int i = 0; i < 8; i++) {
    int idx = base + i;
    if (idx < n) rptr[idx] += add;
  }
  if (b == 0 && t == 0) rptr[n] = E;
}

__global__ __launch_bounds__(256) void csr_fill(const int* __restrict__ src,
                                                const int* __restrict__ dst,
                                                const int* __restrict__ rptr,
                                                int* __restrict__ cursor,
                                                int* __restrict__ eids, int nE) {
  int e = blockIdx.x * 256 + threadIdx.x;
  if (e >= nE) return;
  int d = dst[e];
  int pos = rptr[d] + atomicAdd(&cursor[d], 1);
  eids[pos] = src[e];
}

// ---------------- weight pack: Bt[n][k] bf16, k = [Wself; Wneigh] ----------------
__global__ __launch_bounds__(256) void pack_w(const float* __restrict__ Ws,
                                              const float* __restrict__ Wn,
                                              u16* __restrict__ Bt, int KS, int KT) {
  int t = blockIdx.x * 256 + threadIdx.x;
  if (t >= 256 * KT) return;
  int n = t & 255, k = t >> 8;
  float v = (k < KS) ? Ws[(size_t)k * 256 + n] : Wn[(size_t)(k - KS) * 256 + n];
  Bt[(size_t)n * KT + k] = f2b(v);
}

// ---------------- CSR gather-aggregate + mean (4-deep MLP) ----------------
// layer 0: fp32 source (x), F=128, bf16 out; one wave per row
__global__ __launch_bounds__(256) void agg0(const float* __restrict__ h,
                                            const int* __restrict__ eids,
                                            const int* __restrict__ rptr,
                                            u16* __restrict__ out, int M) {
  int wid = (blockIdx.x * 256 + threadIdx.x) >> 6;
  int lane = threadIdx.x & 63;
  if (wid >= M) return;
  int beg = rptr[wid], end = rptr[wid + 1];
  float a0 = 0.f, a1 = 0.f;
  for (int i = beg; i < end; i += 4) {
    // clamp duplicate ids for tail; mask the accumulate (uniform branches)
    int i1 = (i + 1 < end) ? i + 1 : i;
    int i2 = (i + 2 < end) ? i + 2 : i;
    int i3 = (i + 3 < end) ? i + 3 : i;
    int s0 = eids[i], s1 = eids[i1], s2 = eids[i2], s3 = eids[i3];
    float2 v0 = *reinterpret_cast<const float2*>(&h[(size_t)s0 * IN_ + lane * 2]);
    float2 v1 = *reinterpret_cast<const float2*>(&h[(size_t)s1 * IN_ + lane * 2]);
    float2 v2 = *reinterpret_cast<const float2*>(&h[(size_t)s2 * IN_ + lane * 2]);
    float2 v3 = *reinterpret_cast<const float2*>(&h[(size_t)s3 * IN_ + lane * 2]);
    a0 += v0.x; a1 += v0.y;
    if (i + 1 < end) { a0 += v1.x; a1 += v1.y; }
    if (i + 2 < end) { a0 += v2.x; a1 += v2.y; }
    if (i + 3 < end) { a0 += v3.x; a1 += v3.y; }
  }
  float inv = 1.0f / fmaxf((float)(end - beg), 1.0f);
  u32 p = (u32)f2b(a0 * inv) | ((u32)f2b(a1 * inv) << 16);
  *reinterpret_cast<u32*>(&out[(size_t)wid * IN_ + lane * 2]) = p;
}

// layers 1,2: bf16 source, F=256, bf16 out
__global__ __launch_bounds__(256) void agg1(const u16* __restrict__ h,
                                            const int* __restrict__ eids,
                                            const int* __restrict__ rptr,
                                            u16* __restrict__ out, int M) {
  int wid = (blockIdx.x * 256 + threadIdx.x) >> 6;
  int lane = threadIdx.x & 63;
  if (wid >= M) return;
  int beg = rptr[wid], end = rptr[wid + 1];
  float a0 = 0.f, a1 = 0.f, a2 = 0.f, a3 = 0.f;
  for (int i = beg; i < end; i += 4) {
    int i1 = (i + 1 < end) ? i + 1 : i;
    int i2 = (i + 2 < end) ? i + 2 : i;
    int i3 = (i + 3 < end) ? i + 3 : i;
    int s0 = eids[i], s1 = eids[i1], s2 = eids[i2], s3 = eids[i3];
    u16x4 v0 = *reinterpret_cast<const u16x4*>(&h[(size_t)s0 * HID_ + lane * 4]);
    u16x4 v1 = *reinterpret_cast<const u16x4*>(&h[(size_t)s1 * HID_ + lane * 4]);
    u16x4 v2 = *reinterpret_cast<const u16x4*>(&h[(size_t)s2 * HID_ + lane * 4]);
    u16x4 v3 = *reinterpret_cast<const u16x4*>(&h[(size_t)s3 * HID_ + lane * 4]);
    a0 += b2f(v0[0]); a1 += b2f(v0[1]); a2 += b2f(v0[2]); a3 += b2f(v0[3]);
    if (i + 1 < end) { a0 += b2f(v1[0]); a1 += b2f(v1[1]); a2 += b2f(v1[2]); a3 += b2f(v1[3]); }
    if (i + 2 < end) { a0 += b2f(v2[0]); a1 += b2f(v2[1]); a2 += b2f(v2[2]); a3 += b2f(v2[3]); }
    if (i + 3 < end) { a0 += b2f(v3[0]); a1 += b2f(v3[1]); a2 += b2f(v3[2]); a3 += b2f(v3[3]); }
  }
  float inv = 1.0f / fmaxf((float)(end - beg), 1.0f);
  u16x4 o;
  o[0] = f2b(a0 * inv); o[1] = f2b(a1 * inv); o[2] = f2b(a2 * inv); o[3] = f2b(a3 * inv);
  *reinterpret_cast<u16x4*>(&out[(size_t)wid * HID_ + lane * 4]) = o;
}

// ---------------- MFMA GEMM: out[Mx256] = relu([A0|A1] @ Bt^T + bias) ----------------
template <int KSELF, bool A0F32>
__global__ __launch_bounds__(256) void sage_gemm_mfma(
    const void* __restrict__ A0v, const u16* __restrict__ A1,
    const u16* __restrict__ Bt, const float* __restrict__ bias,
    u16* __restrict__ outp, int M) {
  constexpr int KTOT = 2 * KSELF;
  __shared__ u16 As[64 * 64];    // [m][k], XOR-swizzled
  __shared__ u16 Bs[256 * 64];   // [n][k], XOR-swizzled
  const int tid = threadIdx.x;
  const int lane = tid & 63;
  const int w = tid >> 6;
  const int m0 = blockIdx.x * 64;

  f32x4 acc[4][4];
#pragma unroll
  for (int m = 0; m < 4; m++)
#pragma unroll
    for (int n = 0; n < 4; n++) acc[m][n] = f32x4{0.f, 0.f, 0.f, 0.f};

  for (int kt = 0; kt < KTOT; kt += 64) {
    if (A0F32 && kt < KSELF) {
      const float* A0 = (const float*)A0v;
#pragma unroll
      for (int i = 0; i < 4; i++) {
        int e = tid + i * 256;
        int row = e >> 4;
        int c = (e & 15) * 4;
        int rowg = m0 + row; if (rowg >= M) rowg = M - 1;
        float4 v = *reinterpret_cast<const float4*>(&A0[(size_t)rowg * KSELF + kt + c]);
        u32 p0 = (u32)f2b(v.x) | ((u32)f2b(v.y) << 16);
        u32 p1 = (u32)f2b(v.z) | ((u32)f2b(v.w) << 16);
        int byt = ((row * 64 + c) * 2) ^ ((row & 7) << 4);
        u32* dp = reinterpret_cast<u32*>(reinterpret_cast<char*>(As) + byt);
        dp[0] = p0; dp[1] = p1;
      }
    } else {
      const u16* src; int ksrc;
      if (!A0F32 && kt < KSELF) { src = (const u16*)A0v; ksrc = kt; }
      else                      { src = A1;              ksrc = kt - KSELF; }
#pragma unroll
      for (int i = 0; i < 2; i++) {
        int e = tid + i * 256;
        int row = e >> 3;
        int ch = e & 7;
        int rowg = m0 + row; if (rowg >= M) rowg = M - 1;
        u16x8 v = *reinterpret_cast<const u16x8*>(&src[(size_t)rowg * KSELF + ksrc + ch * 8]);
        int byt = ((row * 64 + ch * 8) * 2) ^ ((row & 7) << 4);
        *reinterpret_cast<u16x8*>(reinterpret_cast<char*>(As) + byt) = v;
      }
    }
#pragma unroll
    for (int i = 0; i < 8; i++) {
      int e = tid + i * 256;
      int n = e >> 3;
      int ch = e & 7;
      u16x8 v = *reinterpret_cast<const u16x8*>(&Bt[(size_t)n * KTOT + kt + ch * 8]);
      int byt = ((n * 64 + ch * 8) * 2) ^ ((n & 7) << 4);
      *reinterpret_cast<u16x8*>(reinterpret_cast<char*>(Bs) + byt) = v;
    }
    __syncthreads();
#pragma unroll
    for (int kk = 0; kk < 64; kk += 32) {
      const int kb = (kk + (lane >> 4) * 8) * 2;
      b16x8 a[4], b[4];
#pragma unroll
      for (int m = 0; m < 4; m++) {
        int row = m * 16 + (lane & 15);
        int byt = (row * 128 + kb) ^ ((row & 7) << 4);
        a[m] = *reinterpret_cast<const b16x8*>(reinterpret_cast<const char*>(As) + byt);
      }
#pragma unroll
      for (int n = 0; n < 4; n++) {
        int row = w * 64 + n * 16 + (lane & 15);
        int byt = (row * 128 + kb) ^ ((row & 7) << 4);
        b[n] = *reinterpret_cast<const b16x8*>(reinterpret_cast<const char*>(Bs) + byt);
      }
#pragma unroll
      for (int m = 0; m < 4; m++)
#pragma unroll
        for (int n = 0; n < 4; n++)
          acc[m][n] = __builtin_amdgcn_mfma_f32_16x16x32_bf16(a[m], b[n], acc[m][n], 0, 0, 0);
    }
    __syncthreads();
  }
  float bv[4];
#pragma unroll
  for (int n = 0; n < 4; n++) bv[n] = bias[w * 64 + n * 16 + (lane & 15)];
#pragma unroll
  for (int m = 0; m < 4; m++) {
    int rowb = m0 + m * 16 + ((lane >> 4) << 2);
#pragma unroll
    for (int r = 0; r < 4; r++) {
      int row = rowb + r;
      if (row < M) {
#pragma unroll
        for (int n = 0; n < 4; n++) {
          float v = acc[m][n][r] + bv[n];
          v = fmaxf(v, 0.0f);
          outp[(size_t)row * 256 + w * 64 + n * 16 + (lane & 15)] = f2b(v);
        }
      }
    }
  }
}

// ---------------- final layer: M=2048, K=512, N=47, fp32 math, no relu ----------------
__global__ __launch_bounds__(64) void sage_gemm_out(
    const u16* __restrict__ h, const u16* __restrict__ hn,
    const float* __restrict__ Ws, const float* __restrict__ Wn,
    const float* __restrict__ bias, float* __restrict__ out) {
  __shared__ float As[512];
  const int row = blockIdx.x;
  const int t = threadIdx.x;
  u16x4 a = *reinterpret_cast<const u16x4*>(&h[(size_t)row * 256 + t * 4]);
  u16x4 b = *reinterpret_cast<const u16x4*>(&hn[(size_t)row * 256 + t * 4]);
#pragma unroll
  for (int j = 0; j < 4; j++) {
    As[t * 4 + j] = b2f(a[j]);
    As[256 + t * 4 + j] = b2f(b[j]);
  }
  __syncthreads();
  if (t < OUT_) {
    float s = bias[t];
#pragma unroll 8
    for (int k = 0; k < 256; k++) s = fmaf(As[k], Ws[k * 47 + t], s);
#pragma unroll 8
    for (int k = 0; k < 256; k++) s = fmaf(As[256 + k], Wn[k * 47 + t], s);
    out[(size_t)row * 47 + t] = s;
  }
}

// ---------------- host driver ----------------
static void build_csr(const int* src, const int* dst, int E, int M,
                      int* cnt, int* cursor, int* rptr, int* bsum, int* eids,
                      hipStream_t stream) {
  const int nb = (M + 2047) / 2048;
  // cnt and cursor are adjacent: one memset for both
  hipMemsetAsync(cnt, 0, (size_t)(200064 + M) * 4, stream);
  hist_kernel<<<(E + 255) / 256, 256, 0, stream>>>(dst, cnt, E);
  scan_local<<<nb, 256, 0, stream>>>(cnt, rptr, bsum, M);
  scan_add<<<nb, 256, 0, stream>>>(rptr, bsum, M, E);
  csr_fill<<<(E + 255) / 256, 256, 0, stream>>>(src, dst, rptr, cursor, eids, E);
}

extern "C" void kernel_launch(void* const* d_in, const int* in_sizes, int n_in,
                              void* d_out, int out_size, void* d_ws, size_t ws_size,
                              hipStream_t stream) {
  const float* x      = (const float*)d_in[0];
  const int*   src0   = (const int*)d_in[1];
  const int*   dst0   = (const int*)d_in[2];
  const int*   src1   = (const int*)d_in[3];
  const int*   dst1   = (const int*)d_in[4];
  const int*   src2   = (const int*)d_in[5];
  const int*   dst2   = (const int*)d_in[6];
  const float* Wself0 = (const float*)d_in[7];
  const float* Wneigh0= (const float*)d_in[8];
  const float* b0     = (const float*)d_in[9];
  const float* Wself1 = (const float*)d_in[10];
  const float* Wneigh1= (const float*)d_in[11];
  const float* b1     = (const float*)d_in[12];
  const float* Wself2 = (const float*)d_in[13];
  const float* Wneigh2= (const float*)d_in[14];
  const float* b2     = (const float*)d_in[15];

  int* wsi   = (int*)d_ws;
  int* cnt   = wsi + OFF_CNT;
  int* cursor= wsi + OFF_CUR;
  int* rptr  = wsi + OFF_RPTR;
  int* bsum  = wsi + OFF_BSUM;
  int* eids  = wsi + OFF_EIDS;
  u16* Bt0   = (u16*)(wsi + OFF_BT0);
  u16* Bt1   = (u16*)(wsi + OFF_BT1);
  u16* HN0   = (u16*)(wsi + OFF_HN0);
  u16* H1    = (u16*)(wsi + OFF_H1);
  u16* HN1   = (u16*)(wsi + OFF_HN1);
  u16* H2    = (u16*)(wsi + OFF_H2);
  u16* HN2   = (u16*)(wsi + OFF_HN2);
  float* out = (float*)d_out;

  pack_w<<<(256 * 256 + 255) / 256, 256, 0, stream>>>(Wself0, Wneigh0, Bt0, IN_, 2 * IN_);
  pack_w<<<(256 * 512 + 255) / 256, 256, 0, stream>>>(Wself1, Wneigh1, Bt1, HID_, 2 * HID_);

  // ---- layer 0 ----
  build_csr(src0, dst0, E0_, N1_, cnt, cursor, rptr, bsum, eids, stream);
  agg0<<<(N1_ + 3) / 4, 256, 0, stream>>>(x, eids, rptr, HN0, N1_);
  sage_gemm_mfma<IN_, true><<<N1_ / 64, 256, 0, stream>>>(x, HN0, Bt0, b0, H1, N1_);

  // ---- layer 1 ----
  build_csr(src1, dst1, E1_, N2_, cnt, cursor, rptr, bsum, eids, stream);
  agg1<<<(N2_ + 3) / 4, 256, 0, stream>>>(H1, eids, rptr, HN1, N2_);
  sage_gemm_mfma<HID_, false><<<(N2_ + 63) / 64, 256, 0, stream>>>(H1, HN1, Bt1, b1, H2, N2_);

  // ---- layer 2 ----
  build_csr(src2, dst2, E2_, N3_, cnt, cursor, rptr, bsum, eids, stream);
  agg1<<<(N3_ + 3) / 4, 256, 0, stream>>>(H2, eids, rptr, HN2, N3_);
  sage_gemm_out<<<N3_, 64, 0, stream>>>(H2, HN2, Wself2, Wneigh2, b2, out);
}

// Round 5
// 561.430 us; speedup vs baseline: 8.4456x; 1.1741x over previous
//
#include <hip/hip_runtime.h>

#define N0_ 1000000
#define N1_ 200000
#define N2_ 20000
#define N3_ 2048
#define E0_ 2000000
#define E1_ 200000
#define E2_ 20480
#define IN_ 128
#define HID_ 256
#define OUT_ 47

typedef unsigned short u16;
typedef unsigned int u32;
typedef __attribute__((ext_vector_type(8))) short b16x8;
typedef __attribute__((ext_vector_type(4))) float f32x4;
typedef __attribute__((ext_vector_type(4))) u16 u16x4;
typedef __attribute__((ext_vector_type(8))) u16 u16x8;

__device__ __forceinline__ u16 f2b(float f) {  // RNE fp32->bf16
  u32 u = __builtin_bit_cast(u32, f);
  return (u16)((u + 0x7FFFu + ((u >> 16) & 1u)) >> 16);
}
__device__ __forceinline__ float b2f(u16 b) {
  return __builtin_bit_cast(float, (u32)b << 16);
}

// ---------------- workspace layout (4-byte words) ----------------
static constexpr size_t OFF_CNT  = 0;          // 200064 (hist counts)
static constexpr size_t OFF_CUR  = 200064;     // 200064 (fill cursors) - adjacent: one memset
static constexpr size_t OFF_RPTR = 400128;     // 200064
static constexpr size_t OFF_BSUM = 600192;     // 128
static constexpr size_t OFF_EIDS = 600320;     // 2000000
static constexpr size_t OFF_BT0  = 2600320;    // 32768  (256x256 bf16)
static constexpr size_t OFF_BT1  = 2633088;    // 65536  (256x512 bf16)
static constexpr size_t OFF_HN0  = 2698624;    // 12800000 (200000x128 bf16)
static constexpr size_t OFF_H1   = 15498624;   // 25600000 (200000x256 bf16)
static constexpr size_t OFF_HN1  = 41098624;   // 2560000  (20000x256 bf16)
static constexpr size_t OFF_H2   = 43658624;   // 2560000
static constexpr size_t OFF_HN2  = 46218624;   // 262144   (2048x256 bf16)

// ---------------- CSR build ----------------
__global__ __launch_bounds__(256) void hist_kernel(const int* __restrict__ dst,
                                                   int* __restrict__ cnt, int nE) {
  int e = blockIdx.x * 256 + threadIdx.x;
  if (e < nE) atomicAdd(&cnt[dst[e]], 1);
}

__global__ __launch_bounds__(256) void scan_local(const int* __restrict__ in,
                                                  int* __restrict__ out,
                                                  int* __restrict__ bsum, int n) {
  __shared__ int s[256];
  const int b = blockIdx.x, t = threadIdx.x;
  const int base = b * 2048 + t * 8;
  int v[8];
  int sum = 0;
#pragma unroll
  for (int i = 0; i < 8; i++) {
    int idx = base + i;
    int x = (idx < n) ? in[idx] : 0;
    v[i] = sum;
    sum += x;
  }
  s[t] = sum;
  __syncthreads();
  for (int off = 1; off < 256; off <<= 1) {
    int x = 0;
    if (t >= off) x = s[t - off];
    __syncthreads();
    if (t >= off) s[t] += x;
    __syncthreads();
  }
  const int texcl = s[t] - sum;
#pragma unroll
  for (int i = 0; i < 8; i++) {
    int idx = base + i;
    if (idx < n) out[idx] = texcl + v[i];
  }
  if (t == 255) bsum[b] = s[255];
}

__global__ __launch_bounds__(256) void scan_add(int* __restrict__ rptr,
                                                const int* __restrict__ bsum,
                                                int n, int E) {
  const int b = blockIdx.x, t = threadIdx.x;
  int add = 0;
  for (int i = 0; i < b; i++) add += bsum[i];
  const int base = b * 2048 + t * 8;
#pragma unroll
  for (int i = 0; i < 8; i++) {
    int idx = base + i;
    if (idx < n) rptr[idx] += add;
  }
  if (b == 0 && t == 0) rptr[n] = E;
}

__global__ __launch_bounds__(256) void csr_fill(const int* __restrict__ src,
                                                const int* __restrict__ dst,
                                                const int* __restrict__ rptr,
                                                int* __restrict__ cursor,
                                                int* __restrict__ eids, int nE) {
  int e = blockIdx.x * 256 + threadIdx.x;
  if (e >= nE) return;
  int d = dst[e];
  int pos = rptr[d] + atomicAdd(&cursor[d], 1);
  eids[pos] = src[e];
}

// ---------------- weight pack: Bt[n][k] bf16, k = [Wself; Wneigh] ----------------
__global__ __launch_bounds__(256) void pack_w(const float* __restrict__ Ws,
                                              const float* __restrict__ Wn,
                                              u16* __restrict__ Bt, int KS, int KT) {
  int t = blockIdx.x * 256 + threadIdx.x;
  if (t >= 256 * KT) return;
  int n = t & 255, k = t >> 8;
  float v = (k < KS) ? Ws[(size_t)k * 256 + n] : Wn[(size_t)(k - KS) * 256 + n];
  Bt[(size_t)n * KT + k] = f2b(v);
}

// ---------------- CSR gather-aggregate + mean ----------------
// 16 edges in flight per wave: lanes 0-31 even edges, 32-63 odd edges,
// each lane loads a 16B slice of the 512B row; halves combined via shfl_xor.
// layer 0: fp32 source (x), F=128
__global__ __launch_bounds__(256) void agg0(const float* __restrict__ h,
                                            const int* __restrict__ eids,
                                            const int* __restrict__ rptr,
                                            u16* __restrict__ out, int M) {
  int wid = (blockIdx.x * 256 + threadIdx.x) >> 6;
  int lane = threadIdx.x & 63;
  if (wid >= M) return;
  const int beg = rptr[wid], end = rptr[wid + 1];
  const int half = lane >> 5;        // 0: even edges, 1: odd edges
  const int col = (lane & 31) * 4;   // fp32 col
  float a0 = 0.f, a1 = 0.f, a2 = 0.f, a3 = 0.f;
  for (int i = beg; i < end; i += 16) {
    int ids[8];
#pragma unroll
    for (int j = 0; j < 8; j++) {
      int idx = i + 2 * j + half;
      idx = idx < end ? idx : end - 1;
      ids[j] = eids[idx];
    }
    float4 v[8];
#pragma unroll
    for (int j = 0; j < 8; j++)
      v[j] = *reinterpret_cast<const float4*>(&h[(size_t)ids[j] * IN_ + col]);
#pragma unroll
    for (int j = 0; j < 8; j++) {
      if (i + 2 * j + half < end) {
        a0 += v[j].x; a1 += v[j].y; a2 += v[j].z; a3 += v[j].w;
      }
    }
  }
  a0 += __shfl_xor(a0, 32, 64);
  a1 += __shfl_xor(a1, 32, 64);
  a2 += __shfl_xor(a2, 32, 64);
  a3 += __shfl_xor(a3, 32, 64);
  if (half == 0) {
    float inv = 1.0f / fmaxf((float)(end - beg), 1.0f);
    u16x4 o;
    o[0] = f2b(a0 * inv); o[1] = f2b(a1 * inv);
    o[2] = f2b(a2 * inv); o[3] = f2b(a3 * inv);
    *reinterpret_cast<u16x4*>(&out[(size_t)wid * IN_ + col]) = o;
  }
}

// layers 1,2: bf16 source, F=256
__global__ __launch_bounds__(256) void agg1(const u16* __restrict__ h,
                                            const int* __restrict__ eids,
                                            const int* __restrict__ rptr,
                                            u16* __restrict__ out, int M) {
  int wid = (blockIdx.x * 256 + threadIdx.x) >> 6;
  int lane = threadIdx.x & 63;
  if (wid >= M) return;
  const int beg = rptr[wid], end = rptr[wid + 1];
  const int half = lane >> 5;
  const int col = (lane & 31) * 8;   // bf16 col
  float a[8];
#pragma unroll
  for (int j = 0; j < 8; j++) a[j] = 0.f;
  for (int i = beg; i < end; i += 16) {
    int ids[8];
#pragma unroll
    for (int j = 0; j < 8; j++) {
      int idx = i + 2 * j + half;
      idx = idx < end ? idx : end - 1;
      ids[j] = eids[idx];
    }
    u16x8 v[8];
#pragma unroll
    for (int j = 0; j < 8; j++)
      v[j] = *reinterpret_cast<const u16x8*>(&h[(size_t)ids[j] * HID_ + col]);
#pragma unroll
    for (int j = 0; j < 8; j++) {
      if (i + 2 * j + half < end) {
#pragma unroll
        for (int c = 0; c < 8; c++) a[c] += b2f(v[j][c]);
      }
    }
  }
#pragma unroll
  for (int c = 0; c < 8; c++) a[c] += __shfl_xor(a[c], 32, 64);
  if (half == 0) {
    float inv = 1.0f / fmaxf((float)(end - beg), 1.0f);
    u16x8 o;
#pragma unroll
    for (int c = 0; c < 8; c++) o[c] = f2b(a[c] * inv);
    *reinterpret_cast<u16x8*>(&out[(size_t)wid * HID_ + col]) = o;
  }
}

// ---------------- MFMA GEMM: out[Mx256] = relu([A0|A1] @ Bt^T + bias) ----------------
// BM=128, BN=256, BK=64; 512 threads = 8 waves (2m x 4n quadrants), 4x4 16x16x32 frags.
template <int KSELF, bool A0F32>
__global__ __launch_bounds__(512) void sage_gemm_mfma(
    const void* __restrict__ A0v, const u16* __restrict__ A1,
    const u16* __restrict__ Bt, const float* __restrict__ bias,
    u16* __restrict__ outp, int M) {
  constexpr int KTOT = 2 * KSELF;
  __shared__ u16 As[128 * 64];   // [m][k], XOR-swizzled, 16 KB
  __shared__ u16 Bs[256 * 64];   // [n][k], XOR-swizzled, 32 KB
  const int tid = threadIdx.x;
  const int lane = tid & 63;
  const int w = tid >> 6;        // 0..7
  const int wm = w >> 2;         // 0..1: m-quadrant
  const int wn = w & 3;          // 0..3: n-quadrant
  const int m0 = blockIdx.x * 128;

  f32x4 acc[4][4];
#pragma unroll
  for (int m = 0; m < 4; m++)
#pragma unroll
    for (int n = 0; n < 4; n++) acc[m][n] = f32x4{0.f, 0.f, 0.f, 0.f};

  for (int kt = 0; kt < KTOT; kt += 64) {
    // ---- stage A tile (128 rows x 64 k) ----
    if (A0F32 && kt < KSELF) {
      const float* A0 = (const float*)A0v;
#pragma unroll
      for (int i = 0; i < 4; i++) {
        int e = tid + i * 512;           // 0..2047 float4s
        int row = e >> 4;
        int c = (e & 15) * 4;
        int rowg = m0 + row; if (rowg >= M) rowg = M - 1;
        float4 v = *reinterpret_cast<const float4*>(&A0[(size_t)rowg * KSELF + kt + c]);
        u32 p0 = (u32)f2b(v.x) | ((u32)f2b(v.y) << 16);
        u32 p1 = (u32)f2b(v.z) | ((u32)f2b(v.w) << 16);
        int byt = ((row * 64 + c) * 2) ^ ((row & 7) << 4);
        u32* dp = reinterpret_cast<u32*>(reinterpret_cast<char*>(As) + byt);
        dp[0] = p0; dp[1] = p1;
      }
    } else {
      const u16* src; int ksrc;
      if (!A0F32 && kt < KSELF) { src = (const u16*)A0v; ksrc = kt; }
      else                      { src = A1;              ksrc = kt - KSELF; }
#pragma unroll
      for (int i = 0; i < 2; i++) {
        int e = tid + i * 512;           // 0..1023 u16x8s
        int row = e >> 3;
        int ch = e & 7;
        int rowg = m0 + row; if (rowg >= M) rowg = M - 1;
        u16x8 v = *reinterpret_cast<const u16x8*>(&src[(size_t)rowg * KSELF + ksrc + ch * 8]);
        int byt = ((row * 64 + ch * 8) * 2) ^ ((row & 7) << 4);
        *reinterpret_cast<u16x8*>(reinterpret_cast<char*>(As) + byt) = v;
      }
    }
    // ---- stage B tile (256 n x 64 k) ----
#pragma unroll
    for (int i = 0; i < 4; i++) {
      int e = tid + i * 512;             // 0..2047 u16x8s
      int n = e >> 3;
      int ch = e & 7;
      u16x8 v = *reinterpret_cast<const u16x8*>(&Bt[(size_t)n * KTOT + kt + ch * 8]);
      int byt = ((n * 64 + ch * 8) * 2) ^ ((n & 7) << 4);
      *reinterpret_cast<u16x8*>(reinterpret_cast<char*>(Bs) + byt) = v;
    }
    __syncthreads();
    // ---- compute: 2 k-slices x 16 MFMA ----
#pragma unroll
    for (int kk = 0; kk < 64; kk += 32) {
      const int kb = (kk + (lane >> 4) * 8) * 2;
      b16x8 a[4], b[4];
#pragma unroll
      for (int m = 0; m < 4; m++) {
        int row = wm * 64 + m * 16 + (lane & 15);
        int byt = (row * 128 + kb) ^ ((row & 7) << 4);
        a[m] = *reinterpret_cast<const b16x8*>(reinterpret_cast<const char*>(As) + byt);
      }
#pragma unroll
      for (int n = 0; n < 4; n++) {
        int row = wn * 64 + n * 16 + (lane & 15);
        int byt = (row * 128 + kb) ^ ((row & 7) << 4);
        b[n] = *reinterpret_cast<const b16x8*>(reinterpret_cast<const char*>(Bs) + byt);
      }
#pragma unroll
      for (int m = 0; m < 4; m++)
#pragma unroll
        for (int n = 0; n < 4; n++)
          acc[m][n] = __builtin_amdgcn_mfma_f32_16x16x32_bf16(a[m], b[n], acc[m][n], 0, 0, 0);
    }
    __syncthreads();
  }
  // ---- epilogue ----
  float bv[4];
#pragma unroll
  for (int n = 0; n < 4; n++) bv[n] = bias[wn * 64 + n * 16 + (lane & 15)];
#pragma unroll
  for (int m = 0; m < 4; m++) {
    int rowb = m0 + wm * 64 + m * 16 + ((lane >> 4) << 2);
#pragma unroll
    for (int r = 0; r < 4; r++) {
      int row = rowb + r;
      if (row < M) {
#pragma unroll
        for (int n = 0; n < 4; n++) {
          float v = acc[m][n][r] + bv[n];
          v = fmaxf(v, 0.0f);
          outp[(size_t)row * 256 + wn * 64 + n * 16 + (lane & 15)] = f2b(v);
        }
      }
    }
  }
}

// ---------------- final layer: M=2048, K=512, N=47, fp32 math, no relu ----------------
__global__ __launch_bounds__(64) void sage_gemm_out(
    const u16* __restrict__ h, const u16* __restrict__ hn,
    const float* __restrict__ Ws, const float* __restrict__ Wn,
    const float* __restrict__ bias, float* __restrict__ out) {
  __shared__ float As[512];
  const int row = blockIdx.x;
  const int t = threadIdx.x;
  u16x4 a = *reinterpret_cast<const u16x4*>(&h[(size_t)row * 256 + t * 4]);
  u16x4 b = *reinterpret_cast<const u16x4*>(&hn[(size_t)row * 256 + t * 4]);
#pragma unroll
  for (int j = 0; j < 4; j++) {
    As[t * 4 + j] = b2f(a[j]);
    As[256 + t * 4 + j] = b2f(b[j]);
  }
  __syncthreads();
  if (t < OUT_) {
    float s = bias[t];
#pragma unroll 8
    for (int k = 0; k < 256; k++) s = fmaf(As[k], Ws[k * 47 + t], s);
#pragma unroll 8
    for (int k = 0; k < 256; k++) s = fmaf(As[256 + k], Wn[k * 47 + t], s);
    out[(size_t)row * 47 + t] = s;
  }
}

// ---------------- host driver ----------------
static void build_csr(const int* src, const int* dst, int E, int M,
                      int* cnt, int* cursor, int* rptr, int* bsum, int* eids,
                      hipStream_t stream) {
  const int nb = (M + 2047) / 2048;
  hipMemsetAsync(cnt, 0, (size_t)(200064 + M) * 4, stream);
  hist_kernel<<<(E + 255) / 256, 256, 0, stream>>>(dst, cnt, E);
  scan_local<<<nb, 256, 0, stream>>>(cnt, rptr, bsum, M);
  scan_add<<<nb, 256, 0, stream>>>(rptr, bsum, M, E);
  csr_fill<<<(E + 255) / 256, 256, 0, stream>>>(src, dst, rptr, cursor, eids, E);
}

extern "C" void kernel_launch(void* const* d_in, const int* in_sizes, int n_in,
                              void* d_out, int out_size, void* d_ws, size_t ws_size,
                              hipStream_t stream) {
  const float* x      = (const float*)d_in[0];
  const int*   src0   = (const int*)d_in[1];
  const int*   dst0   = (const int*)d_in[2];
  const int*   src1   = (const int*)d_in[3];
  const int*   dst1   = (const int*)d_in[4];
  const int*   src2   = (const int*)d_in[5];
  const int*   dst2   = (const int*)d_in[6];
  const float* Wself0 = (const float*)d_in[7];
  const float* Wneigh0= (const float*)d_in[8];
  const float* b0     = (const float*)d_in[9];
  const float* Wself1 = (const float*)d_in[10];
  const float* Wneigh1= (const float*)d_in[11];
  const float* b1     = (const float*)d_in[12];
  const float* Wself2 = (const float*)d_in[13];
  const float* Wneigh2= (const float*)d_in[14];
  const float* b2     = (const float*)d_in[15];

  int* wsi   = (int*)d_ws;
  int* cnt   = wsi + OFF_CNT;
  int* cursor= wsi + OFF_CUR;
  int* rptr  = wsi + OFF_RPTR;
  int* bsum  = wsi + OFF_BSUM;
  int* eids  = wsi + OFF_EIDS;
  u16* Bt0   = (u16*)(wsi + OFF_BT0);
  u16* Bt1   = (u16*)(wsi + OFF_BT1);
  u16* HN0   = (u16*)(wsi + OFF_HN0);
  u16* H1    = (u16*)(wsi + OFF_H1);
  u16* HN1   = (u16*)(wsi + OFF_HN1);
  u16* H2    = (u16*)(wsi + OFF_H2);
  u16* HN2   = (u16*)(wsi + OFF_HN2);
  float* out = (float*)d_out;

  pack_w<<<(256 * 256 + 255) / 256, 256, 0, stream>>>(Wself0, Wneigh0, Bt0, IN_, 2 * IN_);
  pack_w<<<(256 * 512 + 255) / 256, 256, 0, stream>>>(Wself1, Wneigh1, Bt1, HID_, 2 * HID_);

  // ---- layer 0 ----
  build_csr(src0, dst0, E0_, N1_, cnt, cursor, rptr, bsum, eids, stream);
  agg0<<<(N1_ + 3) / 4, 256, 0, stream>>>(x, eids, rptr, HN0, N1_);
  sage_gemm_mfma<IN_, true><<<(N1_ + 127) / 128, 512, 0, stream>>>(x, HN0, Bt0, b0, H1, N1_);

  // ---- layer 1 ----
  build_csr(src1, dst1, E1_, N2_, cnt, cursor, rptr, bsum, eids, stream);
  agg1<<<(N2_ + 3) / 4, 256, 0, stream>>>(H1, eids, rptr, HN1, N2_);
  sage_gemm_mfma<HID_, false><<<(N2_ + 127) / 128, 512, 0, stream>>>(H1, HN1, Bt1, b1, H2, N2_);

  // ---- layer 2 ----
  build_csr(src2, dst2, E2_, N3_, cnt, cursor, rptr, bsum, eids, stream);
  agg1<<<(N3_ + 3) / 4, 256, 0, stream>>>(H2, eids, rptr, HN2, N3_);
  sage_gemm_out<<<N3_, 64, 0, stream>>>(H2, HN2, Wself2, Wneigh2, b2, out);
}